// Round 2
// baseline (325.649 us; speedup 1.0000x reference)
//
#include <hip/hip_runtime.h>

// GraphGatherMol: out[b,f] = relu( (sum_{a < valid_atoms[b]} nf[b,a,f]) * (f < valid_feats[b]) )
// BATCH=4096, MAX_ATOMS=128, N_FEAT=128, fp32.
// Memory-bound: only read rows a < valid_atoms[b] (avg 64.5/128) -> ~135 MB instead of 268 MB.

#define BATCH     4096
#define MAX_ATOMS 128
#define N_FEAT    128

// One block per molecule. 256 threads = 4 waves.
// Thread t: float4-column (t&31), row-group (t>>5) -> 8 rows in flight.
// A wave's 64 lanes cover 2 consecutive rows = 1024 contiguous bytes/instruction.
// 2x manual unroll with independent accumulators -> 2 VMEM loads in flight per thread.
__global__ __launch_bounds__(256, 2) void graph_gather_mol(
    const float* __restrict__ nf,   // [BATCH][MAX_ATOMS][N_FEAT]
    const int*   __restrict__ ds,   // [BATCH][2] = {valid_atoms, valid_feats}
    float*       __restrict__ out)  // [BATCH][N_FEAT]
{
    const int b  = blockIdx.x;
    const int t  = threadIdx.x;
    const int va = ds[b * 2 + 0];   // 1..128
    const int vf = ds[b * 2 + 1];   // 1..128

    const int f4 = t & 31;          // which float4 of the 128-float row
    const int rg = t >> 5;          // row group 0..7

    const float4* base = reinterpret_cast<const float4*>(nf)
                       + (size_t)b * (MAX_ATOMS * (N_FEAT / 4)) + f4;

    float4 acc0 = make_float4(0.f, 0.f, 0.f, 0.f);
    float4 acc1 = make_float4(0.f, 0.f, 0.f, 0.f);

    int a = rg;
    // Unrolled x2: rows a and a+8, independent accumulators.
    for (; a + 8 < va; a += 16) {
        float4 v0 = base[(size_t)a * (N_FEAT / 4)];
        float4 v1 = base[(size_t)(a + 8) * (N_FEAT / 4)];
        acc0.x += v0.x; acc0.y += v0.y; acc0.z += v0.z; acc0.w += v0.w;
        acc1.x += v1.x; acc1.y += v1.y; acc1.z += v1.z; acc1.w += v1.w;
    }
    if (a < va) {
        float4 v0 = base[(size_t)a * (N_FEAT / 4)];
        acc0.x += v0.x; acc0.y += v0.y; acc0.z += v0.z; acc0.w += v0.w;
    }
    acc0.x += acc1.x; acc0.y += acc1.y; acc0.z += acc1.z; acc0.w += acc1.w;

    __shared__ float4 red[256];
    red[t] = acc0;
    __syncthreads();

    if (t < 32) {
        float4 s = red[t];
        #pragma unroll
        for (int g = 1; g < 8; ++g) {
            float4 v = red[g * 32 + t];
            s.x += v.x; s.y += v.y; s.z += v.z; s.w += v.w;
        }
        const int f0 = t * 4;
        s.x = (f0 + 0 < vf) ? fmaxf(s.x, 0.f) : 0.f;
        s.y = (f0 + 1 < vf) ? fmaxf(s.y, 0.f) : 0.f;
        s.z = (f0 + 2 < vf) ? fmaxf(s.z, 0.f) : 0.f;
        s.w = (f0 + 3 < vf) ? fmaxf(s.w, 0.f) : 0.f;
        reinterpret_cast<float4*>(out)[b * (N_FEAT / 4) + t] = s;
    }
}

extern "C" void kernel_launch(void* const* d_in, const int* in_sizes, int n_in,
                              void* d_out, int out_size, void* d_ws, size_t ws_size,
                              hipStream_t stream) {
    const float* nf  = (const float*)d_in[0];
    const int*   ds  = (const int*)d_in[1];
    float*       out = (float*)d_out;
    graph_gather_mol<<<BATCH, 256, 0, stream>>>(nf, ds, out);
}

// Round 4
// 325.633 us; speedup vs baseline: 1.0001x; 1.0001x over previous
//
#include <hip/hip_runtime.h>

// GraphGatherMol: out[b,f] = relu( (sum_{a < valid_atoms[b]} nf[b,a,f]) * (f < valid_feats[b]) )
// BATCH=4096, MAX_ATOMS=128, N_FEAT=128, fp32. Memory-bound.
// Only rows a < valid_atoms[b] are read (avg 64.5/128) -> ~135 MB instead of 268 MB.

#define BATCH     4096
#define MAX_ATOMS 128
#define N_FEAT    128
#define ROW_F4    (N_FEAT / 4)   // 32 float4 per row

// One block per molecule. 256 threads = 4 waves.
// Thread t: float4-column (t&31), row-group (t>>5) -> rows rg, rg+8, rg+16, ...
// 4-way unroll, independent accumulators -> 4 x 16B loads in flight per thread;
// a wave's 64 lanes cover 2 consecutive rows per load = 1024 contiguous B/instr.
__global__ __launch_bounds__(256, 8) void graph_gather_mol(
    const float* __restrict__ nf,   // [BATCH][MAX_ATOMS][N_FEAT]
    const int*   __restrict__ ds,   // [BATCH][2] = {valid_atoms, valid_feats}
    float*       __restrict__ out)  // [BATCH][N_FEAT]
{
    const int b  = blockIdx.x;
    const int t  = threadIdx.x;
    const int va = ds[b * 2 + 0];   // 1..128
    const int vf = ds[b * 2 + 1];   // 1..128

    const int f4 = t & 31;
    const int rg = t >> 5;          // 0..7

    const float4* base = reinterpret_cast<const float4*>(nf)
                       + (size_t)b * (MAX_ATOMS * ROW_F4) + f4;

    float4 a0 = make_float4(0.f, 0.f, 0.f, 0.f);
    float4 a1 = make_float4(0.f, 0.f, 0.f, 0.f);
    float4 a2 = make_float4(0.f, 0.f, 0.f, 0.f);
    float4 a3 = make_float4(0.f, 0.f, 0.f, 0.f);

    int a = rg;
    // Main: 4 rows per thread per iter (stride 8), all 4 loads independent.
    for (; a + 24 < va; a += 32) {
        float4 v0 = base[(size_t)(a     ) * ROW_F4];
        float4 v1 = base[(size_t)(a +  8) * ROW_F4];
        float4 v2 = base[(size_t)(a + 16) * ROW_F4];
        float4 v3 = base[(size_t)(a + 24) * ROW_F4];
        a0.x += v0.x; a0.y += v0.y; a0.z += v0.z; a0.w += v0.w;
        a1.x += v1.x; a1.y += v1.y; a1.z += v1.z; a1.w += v1.w;
        a2.x += v2.x; a2.y += v2.y; a2.z += v2.z; a2.w += v2.w;
        a3.x += v3.x; a3.y += v3.y; a3.z += v3.z; a3.w += v3.w;
    }
    // Remainder: up to 3 more rows (stride 8).
    for (; a < va; a += 8) {
        float4 v = base[(size_t)a * ROW_F4];
        a0.x += v.x; a0.y += v.y; a0.z += v.z; a0.w += v.w;
    }
    a0.x += a1.x + a2.x + a3.x;
    a0.y += a1.y + a2.y + a3.y;
    a0.z += a1.z + a2.z + a3.z;
    a0.w += a1.w + a2.w + a3.w;

    __shared__ float4 red[256];
    red[t] = a0;
    __syncthreads();

    if (t < 32) {
        float4 s = red[t];
        #pragma unroll
        for (int g = 1; g < 8; ++g) {
            float4 v = red[g * 32 + t];
            s.x += v.x; s.y += v.y; s.z += v.z; s.w += v.w;
        }
        const int f0 = t * 4;
        s.x = (f0 + 0 < vf) ? fmaxf(s.x, 0.f) : 0.f;
        s.y = (f0 + 1 < vf) ? fmaxf(s.y, 0.f) : 0.f;
        s.z = (f0 + 2 < vf) ? fmaxf(s.z, 0.f) : 0.f;
        s.w = (f0 + 3 < vf) ? fmaxf(s.w, 0.f) : 0.f;
        reinterpret_cast<float4*>(out)[b * ROW_F4 + t] = s;
    }
}

extern "C" void kernel_launch(void* const* d_in, const int* in_sizes, int n_in,
                              void* d_out, int out_size, void* d_ws, size_t ws_size,
                              hipStream_t stream) {
    const float* nf  = (const float*)d_in[0];
    const int*   ds  = (const int*)d_in[1];
    float*       out = (float*)d_out;
    graph_gather_mol<<<BATCH, 256, 0, stream>>>(nf, ds, out);
}